// Round 1
// baseline (206.597 us; speedup 1.0000x reference)
//
#include <hip/hip_runtime.h>

typedef unsigned short u16;
typedef unsigned int u32;
typedef __bf16 bf16x8 __attribute__((ext_vector_type(8)));
typedef float f32x4 __attribute__((ext_vector_type(4)));

#define DEV __device__ __forceinline__

// Problem constants (B,T,D_MODEL,H) = (2,2048,1024,16)
constexpr int BB = 2;
constexpr int TT = 2048;
constexpr int CD = 1024;
constexpr int HH = 16;
constexpr int DH = 64;
constexpr int BT = BB * TT;   // 4096

// softmax scale 1/8 folded with log2(e): S' = S/8*log2e, exp(x)=exp2(x')
#define QSCALE 0.18033688011112042f

DEV u16 f2bf(float f) {
    u32 u = __builtin_bit_cast(u32, f);
    u32 r = u + 0x7FFFu + ((u >> 16) & 1u);
    return (u16)(r >> 16);
}

DEV f32x4 mfma16(bf16x8 a, bf16x8 b, f32x4 c) {
    return __builtin_amdgcn_mfma_f32_16x16x32_bf16(a, b, c, 0, 0, 0);
}

// Async global->LDS, 16B per lane: LDS dest = wave-uniform base + lane*16.
DEV void gld_lds16(u16* lds, const u16* g) {
    __builtin_amdgcn_global_load_lds(
        (const __attribute__((address_space(1))) unsigned int*)g,
        (__attribute__((address_space(3))) unsigned int*)lds, 16, 0, 0);
}

// ---------------------------------------------------------------------------
// Fused preprocessing (single launch):
//   blocks [0,2048):      x fp32 -> bf16           (4096x1024)
//   blocks [2048,5120):   W_qkv (1024x3072) -> transposed bf16 (3072x1024)
//   blocks [5120,6144):   W_o   (1024x1024) -> transposed bf16 (1024x1024)
// ---------------------------------------------------------------------------
__global__ __launch_bounds__(256)
void prep_kernel(const float* __restrict__ x, u16* __restrict__ xb,
                 const float* __restrict__ Wqkv, u16* __restrict__ WqkvT,
                 const float* __restrict__ Wo, u16* __restrict__ WoT) {
    const int tid = threadIdx.x;
    int blk = blockIdx.x;
    if (blk < 2048) {                       // convert job
        const int i = (blk * 256 + tid) * 8;
        float4 a = *(const float4*)&x[i];
        float4 b = *(const float4*)&x[i + 4];
        u16 t[8];
        t[0] = f2bf(a.x); t[1] = f2bf(a.y); t[2] = f2bf(a.z); t[3] = f2bf(a.w);
        t[4] = f2bf(b.x); t[5] = f2bf(b.y); t[6] = f2bf(b.z); t[7] = f2bf(b.w);
        *(uint4*)&xb[i] = *(const uint4*)t;
        return;                             // whole block exits (no barrier)
    }
    __shared__ u16 tile[32][33];
    const float* in; u16* out; int rows, cols, bx, by;
    if (blk < 5120) { blk -= 2048; in = Wqkv; out = WqkvT; rows = 1024; cols = 3072; bx = blk % 96; by = blk / 96; }
    else            { blk -= 5120; in = Wo;   out = WoT;   rows = 1024; cols = 1024; bx = blk % 32; by = blk / 32; }
    const int c0 = bx * 32, r0 = by * 32;
    const int tx = tid & 31, ty = tid >> 5;
    #pragma unroll
    for (int i = ty; i < 32; i += 8)
        tile[i][tx] = f2bf(in[(r0 + i) * cols + (c0 + tx)]);
    __syncthreads();
    #pragma unroll
    for (int i = ty; i < 32; i += 8)
        out[(c0 + i) * rows + (r0 + tx)] = tile[tx][i];
}

// ---------------------------------------------------------------------------
// QKV GEMM: 256x256 tile, BK=64, 8 waves (2M x 4N), 8-phase schedule.
//   C[M=4096][N=3072] = xb * WqkvT^T, scattered to Q (pre-scaled) / K / V^T.
// Techniques (guide §5/§5.5): T1 XCD-chunked swizzle (192%8==0, bijective);
// T2 LDS XOR chunk-swizzle (chunk ^= row&7), applied both-sides: linear
// global_load_lds dest + inverse-swizzled per-lane GLOBAL source + swizzled
// ds_read addr; T3/T4 8-phase with counted vmcnt(4) (never 0 mid-loop);
// T5 s_setprio(1) around each 16-MFMA cluster.
//
// LDS: As/Bs[2][256][64] bf16 = 128 KiB (1 block/CU). Per wave: 128x64 out,
// acc[8][4] f32x4. Per K-tile (4 phases): phase a reads fa-lo(8)+fbL(4),
// b reads fbH(4), c reads fa-hi(8), d reads none  (12/4/8/0 ds_read_b128).
//
// Staging slots (1 half-tile = 2 gld_lds/wave per slot), steady state:
//   p1: buf1.A0<-t(2i+1)  p2: buf1.A1<-t(2i+1)   (tile o, needed @p5)
//   p3: buf0.B0<-t(2i+2)  p4: buf0.B1  p5: buf0.A0  p6: buf0.A1 (needed @p1')
//   p7: buf1.B0<-t(2i+3)  p8: buf1.B1
// vmcnt(4) at end of p4 (covers tile o: last stage p2, +p3/p4 in flight)
// and p8 (covers tile e+2: last stage p6, +p7/p8 in flight). WAR: every
// stage slot is >=1 barrier after the last ds_read of its region.
// ---------------------------------------------------------------------------
__global__ __launch_bounds__(512, 2)
void gemm_qkv(const u16* __restrict__ A, const u16* __restrict__ Bt,
              u16* __restrict__ Qo, u16* __restrict__ Ko, u16* __restrict__ Vo) {
    __shared__ alignas(16) u16 As[2][256 * 64];
    __shared__ alignas(16) u16 Bs[2][256 * 64];

    const int tid = threadIdx.x;
    const int wave = tid >> 6, lane = tid & 63;
    const int quad = lane >> 4, l16 = lane & 15;
    const int wm = (wave & 1) * 128, wn = (wave >> 1) * 64;

    int bid = (int)blockIdx.x;
    bid = (bid & 7) * 24 + (bid >> 3);      // 192 blocks -> 24 per XCD, chunked
    const int bx = bid % 12, by = bid / 12;
    const int m0 = by * 256, n0 = bx * 256;

    // Per-lane pre-swizzled global staging address. gld_lds lane l writes LDS
    // row (+l>>3), phys chunk (l&7); stored logical chunk = phys ^ (row&7),
    // so fetch logical chunk (l&7)^((l>>3)&7).  row&7 == (l>>3)&7 for all
    // slots since every region base row is a multiple of 8.
    const int srow = wave * 8 + (lane >> 3);
    const int schunk = ((lane & 7) ^ ((lane >> 3) & 7)) * 8;
    const u16* gA = A  + (size_t)(m0 + srow) * CD + schunk;
    const u16* gB = Bt + (size_t)(n0 + srow) * CD + schunk;

    // stage one 128-row half-tile (h) of K-tile t: 2 issues of 64 rows
    auto stage = [&](u16* ldsbuf, const u16* g, int h, int t) {
        const u16* gg = g + (size_t)(h * 128) * CD + t * 64;
        u16* ll = ldsbuf + (h * 128 + wave * 8) * 64;   // wave-uniform base
        gld_lds16(ll, gg);
        gld_lds16(ll + 64 * 64, gg + (size_t)64 * CD);
    };
    // swizzled ds_read_b128: logical chunk c at row r lives at c^(r&7);
    // r&7 == l16&7  =>  16 lanes of a quad spread over all 8 bank groups.
    auto rdA = [&](bf16x8* f, const u16* buf, int mh) {
        #pragma unroll
        for (int mt = 0; mt < 4; ++mt)
            #pragma unroll
            for (int ks = 0; ks < 2; ++ks) {
                const int r = wm + mh * 64 + mt * 16 + l16;
                f[mt * 2 + ks] = *(const bf16x8*)
                    &buf[r * 64 + (((ks * 4 + quad) ^ (l16 & 7)) << 3)];
            }
    };
    auto rdB = [&](bf16x8* f, const u16* buf, int nh) {
        #pragma unroll
        for (int nt = 0; nt < 2; ++nt)
            #pragma unroll
            for (int ks = 0; ks < 2; ++ks) {
                const int r = wn + nh * 32 + nt * 16 + l16;
                f[nt * 2 + ks] = *(const bf16x8*)
                    &buf[r * 64 + (((ks * 4 + quad) ^ (l16 & 7)) << 3)];
            }
    };

    f32x4 acc[8][4] = {};
    auto mmq = [&](const bf16x8* fa, const bf16x8* fb, int mh, int nh) {
        __builtin_amdgcn_s_setprio(1);
        #pragma unroll
        for (int ks = 0; ks < 2; ++ks)           // ks outer: 8 indep, then 8
            #pragma unroll
            for (int mt = 0; mt < 4; ++mt)
                #pragma unroll
                for (int nt = 0; nt < 2; ++nt)
                    acc[mh * 4 + mt][nh * 2 + nt] =
                        mfma16(fa[mt * 2 + ks], fb[nt * 2 + ks],
                               acc[mh * 4 + mt][nh * 2 + nt]);
        __builtin_amdgcn_s_setprio(0);
    };

    // prologue: tiles 0 (buf0) and 1 (buf1) = 16 issues/wave
    stage(As[0], gA, 0, 0); stage(As[0], gA, 1, 0);
    stage(Bs[0], gB, 0, 0); stage(Bs[0], gB, 1, 0);
    stage(As[1], gA, 0, 1); stage(As[1], gA, 1, 1);
    stage(Bs[1], gB, 0, 1); stage(Bs[1], gB, 1, 1);
    asm volatile("s_waitcnt vmcnt(8)" ::: "memory");   // tile0 landed
    __builtin_amdgcn_s_barrier();

    bf16x8 fa[8], fbL[4], fbH[4];

    for (int i = 0; i < 8; ++i) {           // 16 K-tiles, 2 per iteration
        // ---- p1: tile e=2i (buf0), quad (m-lo, n-lo) ----
        rdA(fa, As[0], 0);
        rdB(fbL, Bs[0], 0);
        if (i >= 1) stage(As[1], gA, 0, 2 * i + 1);
        __builtin_amdgcn_s_barrier();
        asm volatile("s_waitcnt lgkmcnt(0)" ::: "memory");
        mmq(fa, fbL, 0, 0);
        __builtin_amdgcn_s_barrier();
        // ---- p2: quad (m-lo, n-hi) ----
        rdB(fbH, Bs[0], 1);
        if (i >= 1) stage(As[1], gA, 1, 2 * i + 1);
        __builtin_amdgcn_s_barrier();
        asm volatile("s_waitcnt lgkmcnt(0)" ::: "memory");
        mmq(fa, fbH, 0, 1);
        __builtin_amdgcn_s_barrier();
        // ---- p3: quad (m-hi, n-hi) ----
        rdA(fa, As[0], 1);
        if (i <= 6) stage(Bs[0], gB, 0, 2 * i + 2);
        __builtin_amdgcn_s_barrier();
        asm volatile("s_waitcnt lgkmcnt(0)" ::: "memory");
        mmq(fa, fbH, 1, 1);
        __builtin_amdgcn_s_barrier();
        // ---- p4: quad (m-hi, n-lo); vmcnt checkpoint for tile o ----
        if (i <= 6) stage(Bs[0], gB, 1, 2 * i + 2);
        __builtin_amdgcn_s_barrier();
        mmq(fa, fbL, 1, 0);
        if (i < 7) { asm volatile("s_waitcnt vmcnt(4)" ::: "memory"); }
        else       { asm volatile("s_waitcnt vmcnt(0)" ::: "memory"); }
        __builtin_amdgcn_s_barrier();
        // ---- p5: tile o=2i+1 (buf1), quad (m-lo, n-lo) ----
        rdA(fa, As[1], 0);
        rdB(fbL, Bs[1], 0);
        if (i <= 6) stage(As[0], gA, 0, 2 * i + 2);
        __builtin_amdgcn_s_barrier();
        asm volatile("s_waitcnt lgkmcnt(0)" ::: "memory");
        mmq(fa, fbL, 0, 0);
        __builtin_amdgcn_s_barrier();
        // ---- p6: quad (m-lo, n-hi) ----
        rdB(fbH, Bs[1], 1);
        if (i <= 6) stage(As[0], gA, 1, 2 * i + 2);
        __builtin_amdgcn_s_barrier();
        asm volatile("s_waitcnt lgkmcnt(0)" ::: "memory");
        mmq(fa, fbH, 0, 1);
        __builtin_amdgcn_s_barrier();
        // ---- p7: quad (m-hi, n-hi) ----
        rdA(fa, As[1], 1);
        if (i <= 6) stage(Bs[1], gB, 0, 2 * i + 3);
        __builtin_amdgcn_s_barrier();
        asm volatile("s_waitcnt lgkmcnt(0)" ::: "memory");
        mmq(fa, fbH, 1, 1);
        __builtin_amdgcn_s_barrier();
        // ---- p8: quad (m-hi, n-lo); vmcnt checkpoint for tile e+2 ----
        if (i <= 6) stage(Bs[1], gB, 1, 2 * i + 3);
        __builtin_amdgcn_s_barrier();
        mmq(fa, fbL, 1, 0);
        if (i < 7) { asm volatile("s_waitcnt vmcnt(4)" ::: "memory"); }
        __builtin_amdgcn_s_barrier();
    }

    // Epilogue. C/D layout: row = quad*4+reg (m), col = l16 (n).
    // which = c>>10 is block-uniform (256 | 1024).
    #pragma unroll
    for (int mt = 0; mt < 8; ++mt) {
        #pragma unroll
        for (int nt = 0; nt < 4; ++nt) {
            #pragma unroll
            for (int reg = 0; reg < 4; ++reg) {
                const int r = m0 + wm + mt * 16 + quad * 4 + reg;
                const int c = n0 + wn + nt * 16 + l16;
                const int which = c >> 10;       // 0=q 1=k 2=v
                const int cc = c & 1023;
                const int h = cc >> 6, d = cc & 63;
                const int b = r >> 11, t = r & 2047;
                const int bh = b * HH + h;
                if (which == 0) {
                    Qo[((size_t)bh * TT + t) * DH + d] =
                        f2bf(acc[mt][nt][reg] * QSCALE);
                } else if (which == 1) {
                    Ko[((size_t)bh * TT + t) * DH + d] = f2bf(acc[mt][nt][reg]);
                } else {
                    Vo[((size_t)bh * DH + d) * TT + t] = f2bf(acc[mt][nt][reg]);
                }
            }
        }
    }
}

// ---------------------------------------------------------------------------
// GEMM: C[M][N] = A[M][K] * Bt[N][K]^T,  bf16 in, fp32 acc.  (out-projection)
// BM=128, BN template, BK=32, global_load_lds width-16 staging.
// ---------------------------------------------------------------------------
template <int EPI, int BN>
__global__ __launch_bounds__(256)
void gemm_bt(const u16* __restrict__ A, const u16* __restrict__ Bt,
             u16* __restrict__ out0, u16* __restrict__ out1,
             u16* __restrict__ out2, float* __restrict__ outf,
             int M, int N, int K) {
    constexpr int BM = 128, BK = 32, AST = 32;
    constexpr int NT = BN / 32;             // n-tiles per wave
    __shared__ alignas(16) u16 As[BM * AST];
    __shared__ alignas(16) u16 Bs[BN * AST];

    const int tid  = threadIdx.x;
    const int wave = tid >> 6, lane = tid & 63;
    const int quad = lane >> 4, l16 = lane & 15;
    const int wm = (wave & 1) * 64, wn = (wave >> 1) * (BN / 2);
    const int m0 = blockIdx.y * BM, n0 = blockIdx.x * BN;

    // DMA staging: one instr = 64 lanes x 16B = 16 rows x 64B.
    const int srowA = wave * 32 + (lane >> 2);
    const int srowB = wave * (BN / 4) + (lane >> 2);
    const int scol  = (lane & 3) * 8;
    const u16* ga0 = A  + (size_t)(m0 + srowA) * K + scol;
    const u16* ga1 = ga0 + (size_t)16 * K;
    const u16* gb0 = Bt + (size_t)(n0 + srowB) * K + scol;
    const u16* gb1 = gb0 + (size_t)16 * K;
    u16* la0 = As + wave * 1024;
    u16* la1 = As + wave * 1024 + 512;
    u16* lb0 = Bs + wave * (BN * 8);
    u16* lb1 = Bs + wave * (BN * 8) + 512;

    f32x4 acc[4][NT] = {};

    for (int k0 = 0; k0 < K; k0 += BK) {
        gld_lds16(la0, ga0 + k0);
        gld_lds16(la1, ga1 + k0);
        gld_lds16(lb0, gb0 + k0);
        if constexpr (BN == 128) gld_lds16(lb1, gb1 + k0);
        __syncthreads();

        bf16x8 fa[4], fb[NT];
        #pragma unroll
        for (int mt = 0; mt < 4; ++mt)
            fa[mt] = *(const bf16x8*)&As[(wm + mt * 16 + l16) * AST + quad * 8];
        #pragma unroll
        for (int nt = 0; nt < NT; ++nt)
            fb[nt] = *(const bf16x8*)&Bs[(wn + nt * 16 + l16) * AST + quad * 8];
        #pragma unroll
        for (int mt = 0; mt < 4; ++mt)
            #pragma unroll
            for (int nt = 0; nt < NT; ++nt)
                acc[mt][nt] = mfma16(fa[mt], fb[nt], acc[mt][nt]);
        __syncthreads();
    }

    // Epilogue. C/D layout: row = quad*4+reg, col = l16.
    #pragma unroll
    for (int mt = 0; mt < 4; ++mt) {
        #pragma unroll
        for (int nt = 0; nt < NT; ++nt) {
            #pragma unroll
            for (int reg = 0; reg < 4; ++reg) {
                const int r = m0 + wm + mt * 16 + quad * 4 + reg;
                const int c = n0 + wn + nt * 16 + l16;
                if (EPI == 0) {
                    outf[(size_t)r * N + c] = acc[mt][nt][reg];
                } else {
                    const int which = c >> 10;       // 0=q 1=k 2=v
                    const int cc = c & 1023;
                    const int h = cc >> 6, d = cc & 63;
                    const int b = r >> 11, t = r & 2047;
                    const int bh = b * HH + h;
                    if (which == 0) {
                        out0[((size_t)bh * TT + t) * DH + d] =
                            f2bf(acc[mt][nt][reg] * QSCALE);
                    } else if (which == 1) {
                        out1[((size_t)bh * TT + t) * DH + d] = f2bf(acc[mt][nt][reg]);
                    } else {
                        out2[((size_t)bh * DH + d) * TT + t] = f2bf(acc[mt][nt][reg]);
                    }
                }
            }
        }
    }
}

// ---------------------------------------------------------------------------
// Flash attention v4 (causal): S^T formulation + paired-key full-K=32 PV.
//   S^T = K·Q^T  ->  C[key = quad*4+reg (tile nt)][q = l16]; per-lane scalar
//   softmax state in exp2 domain (scale+log2e pre-folded into Q).
//   PV uses the MFMA k-permutation freedom: logical k=quad*8+j maps to
//   physical key pair*32 + (j<4 ? quad*4+j : 16+quad*4+(j-4)) on BOTH
//   operands (cancels). P^T comes directly from the two C-layout S-tiles;
//   V^T LDS columns are stored pair-permuted so fragments are one b128.
// Grid (16, B*H); block p handles q-tiles 31-p and p (33 steps, balanced).
// K/V double-buffered in LDS; next chunk prefetched to registers; K/V
// fragments hoisted once per chunk and shared by both q-tiles.
// ---------------------------------------------------------------------------
constexpr int KST = 72;  // K/V LDS row stride (144 B, rows 16B-aligned)

DEV void attn_step(const bf16x8 fk[4][2], const bf16x8 fv[2][4],
                   const bf16x8* fq, f32x4* Oacc,
                   float& m_i, float& l_i, bool diag,
                   int wave, int quad, int l16) {
    // S^T: 4 key-tiles x 2 k-steps over d
    f32x4 st[4];
    #pragma unroll
    for (int nt = 0; nt < 4; ++nt) {
        f32x4 t = {};
        t = mfma16(fk[nt][0], fq[0], t);   // A=K (m=key), B=Q (n=q)
        t = mfma16(fk[nt][1], fq[1], t);
        st[nt] = t;
    }

    // causal mask on diagonal tile: key_loc <= q_loc
    if (diag) {
        const int qg = wave * 16 + l16;
        #pragma unroll
        for (int nt = 0; nt < 4; ++nt)
            #pragma unroll
            for (int reg = 0; reg < 4; ++reg) {
                const int kg = nt * 16 + quad * 4 + reg;
                st[nt][reg] = (kg <= qg) ? st[nt][reg] : -INFINITY;
            }
    }

    // row max: 15 in-register + 2 cross-quad shuffles (lane = quad*16+l16)
    float vmax = st[0][0];
    #pragma unroll
    for (int nt = 0; nt < 4; ++nt)
        #pragma unroll
        for (int reg = 0; reg < 4; ++reg)
            vmax = fmaxf(vmax, st[nt][reg]);
    vmax = fmaxf(vmax, __shfl_xor(vmax, 16, 64));
    vmax = fmaxf(vmax, __shfl_xor(vmax, 32, 64));

    const float mnew = fmaxf(m_i, vmax);
    const float alpha = __builtin_amdgcn_exp2f(m_i - mnew);
    m_i = mnew;

    float vsum = 0.f;
    #pragma unroll
    for (int nt = 0; nt < 4; ++nt)
        #pragma unroll
        for (int reg = 0; reg < 4; ++reg) {
            const float p = __builtin_amdgcn_exp2f(st[nt][reg] - mnew);
            st[nt][reg] = p;
            vsum += p;
        }
    vsum += __shfl_xor(vsum, 16, 64);
    vsum += __shfl_xor(vsum, 32, 64);
    l_i = l_i * alpha + vsum;

    #pragma unroll
    for (int dt = 0; dt < 4; ++dt)
        #pragma unroll
        for (int reg = 0; reg < 4; ++reg)
            Oacc[dt][reg] *= alpha;

    // P^T B-operand: reg j<4 = st[2p][j] (key p*32+quad*4+j),
    //                reg j>=4 = st[2p+1][j-4] (key p*32+16+quad*4+j-4)
    #pragma unroll
    for (int pair = 0; pair < 2; ++pair) {
        u16 pa[8];
        #pragma unroll
        for (int j = 0; j < 4; ++j) {
            pa[j]     = f2bf(st[2 * pair][j]);
            pa[4 + j] = f2bf(st[2 * pair + 1][j]);
        }
        const bf16x8 pb = *(const bf16x8*)pa;
        #pragma unroll
        for (int dt = 0; dt < 4; ++dt)
            Oacc[dt] = mfma16(fv[pair][dt], pb, Oacc[dt]);
    }
}

__global__ __launch_bounds__(256, 2)
void attn_kernel(const u16* __restrict__ Q, const u16* __restrict__ Kb,
                 const u16* __restrict__ Vt, u16* __restrict__ O) {
    __shared__ alignas(16) u16 Ks[2][64 * KST];
    __shared__ alignas(16) u16 Vs[2][64 * KST];

    const int p = blockIdx.x;         // 0..15
    const int bh = blockIdx.y;
    const int qtA = 31 - p;           // big tile; also jmax
    const int qtB = p;                // small tile
    const int jmax = qtA;

    const int tid = threadIdx.x;
    const int wave = tid >> 6, lane = tid & 63;
    const int quad = lane >> 4, l16 = lane & 15;

    const u16* Qh = Q  + (size_t)bh * TT * DH;
    const u16* Kh = Kb + (size_t)bh * TT * DH;
    const u16* Vh = Vt + (size_t)bh * DH * TT;

    const int rowA = qtA * 64 + wave * 16;
    const int rowB = qtB * 64 + wave * 16;

    // Q fragments (B-operand: n = l16 = q, k = quad*8+j over d)
    bf16x8 fqA[2], fqB[2];
    fqA[0] = *(const bf16x8*)&Qh[(rowA + l16) * DH + quad * 8];
    fqA[1] = *(const bf16x8*)&Qh[(rowA + l16) * DH + 32 + quad * 8];
    fqB[0] = *(const bf16x8*)&Qh[(rowB + l16) * DH + quad * 8];
    fqB[1] = *(const bf16x8*)&Qh[(rowB + l16) * DH + 32 + quad * 8];

    f32x4 OA[4] = {}, OB[4] = {};
    float mA = -INFINITY, lA = 0.f, mB = -INFINITY, lB = 0.f;

    // Chunk staging: thread i covers 16B at row (i>>3), col (i&7)*8, +row32.
    const int trow = tid >> 3;
    const int ic   = tid & 7;            // 8-key group index
    const int tcol = ic * 8;
    // V pair-permuted destination column for this thread's 8 keys:
    //   keys 8*ic..8*ic+7 -> cols c1..c1+3 and c1+8..c1+11
    const int vc1 = 32 * (ic >> 2) + 16 * (ic & 1) + 4 * ((ic & 3) >> 1);
    uint4 kr0, kr1, vr0, vr1;

    auto load_chunk = [&](int j) {
        const u16* ks = Kh + (size_t)j * 64 * DH;
        kr0 = *(const uint4*)&ks[trow * DH + tcol];
        kr1 = *(const uint4*)&ks[(trow + 32) * DH + tcol];
        const u16* vs = Vh + (size_t)j * 64;
        vr0 = *(const uint4*)&vs[(size_t)trow * TT + tcol];
        vr1 = *(const uint4*)&vs[(size_t)(trow + 32) * TT + tcol];
    };
    auto write_chunk = [&](int buf) {
        *(uint4*)&Ks[buf][trow * KST + tcol]        = kr0;
        *(uint4*)&Ks[buf][(trow + 32) * KST + tcol] = kr1;
        // V: split each 16B into two 8B halves at permuted columns
        *(uint2*)&Vs[buf][trow * KST + vc1]            = *(const uint2*)&vr0;
        *(uint2*)&Vs[buf][trow * KST + vc1 + 8]        = *((const uint2*)&vr0 + 1);
        *(uint2*)&Vs[buf][(trow + 32) * KST + vc1]     = *(const uint2*)&vr1;
        *(uint2*)&Vs[buf][(trow + 32) * KST + vc1 + 8] = *((const uint2*)&vr1 + 1);
    };

    load_chunk(0);
    write_chunk(0);

    for (int j = 0; j <= jmax; ++j) {
        const int cur = j & 1;
        __syncthreads();                    // buf[cur] staged & visible
        if (j < jmax) load_chunk(j + 1);    // loads fly during compute

        // Hoist K/V fragments once per chunk (shared by both q-tiles)
        bf16x8 fk[4][2], fv[2][4];
        #pragma unroll
        for (int nt = 0; nt < 4; ++nt) {
            fk[nt][0] = *(const bf16x8*)&Ks[cur][(nt * 16 + l16) * KST + quad * 8];
            fk[nt][1] = *(const bf16x8*)&Ks[cur][(nt * 16 + l16) * KST + 32 + quad * 8];
        }
        #pragma unroll
        for (int pair = 0; pair < 2; ++pair)
            #pragma unroll
            for (int dt = 0; dt < 4; ++dt)
                fv[pair][dt] = *(const bf16x8*)
                    &Vs[cur][(dt * 16 + l16) * KST + pair * 32 + quad * 8];

        attn_step(fk, fv, fqA, OA, mA, lA, (j == qtA), wave, quad, l16);
        if (j <= qtB)
            attn_step(fk, fv, fqB, OB, mB, lB, (j == qtB), wave, quad, l16);
        if (j < jmax) write_chunk(cur ^ 1); // after all buf[cur^1] readers done
    }

    // Epilogue: O^T rows d = dt*16+quad*4+reg, col q = l16; write (B,T,C).
    const int b = bh >> 4, h = bh & 15;
    const float rA = 1.f / lA, rB = 1.f / lB;
    #pragma unroll
    for (int dt = 0; dt < 4; ++dt) {
        u16 oa[4], ob[4];
        #pragma unroll
        for (int reg = 0; reg < 4; ++reg) {
            oa[reg] = f2bf(OA[dt][reg] * rA);
            ob[reg] = f2bf(OB[dt][reg] * rB);
        }
        *(uint2*)&O[((size_t)(b * TT + rowA + l16)) * CD + h * DH + dt * 16 + quad * 4] =
            *(const uint2*)oa;
        *(uint2*)&O[((size_t)(b * TT + rowB + l16)) * CD + h * DH + dt * 16 + quad * 4] =
            *(const uint2*)ob;
    }
}

// ---------------------------------------------------------------------------
extern "C" void kernel_launch(void* const* d_in, const int* in_sizes, int n_in,
                              void* d_out, int out_size, void* d_ws, size_t ws_size,
                              hipStream_t stream) {
    (void)in_sizes; (void)n_in; (void)out_size; (void)ws_size;
    const float* x    = (const float*)d_in[0];   // (4096, 1024) fp32
    const float* Wqkv = (const float*)d_in[1];   // (1024, 3072) fp32
    const float* Wo   = (const float*)d_in[2];   // (1024, 1024) fp32
    float* out = (float*)d_out;                  // (4096, 1024) fp32

    char* ws = (char*)d_ws;
    u16* xb    = (u16*)(ws + 0);                    // 4096x1024  (8 MB)
    u16* WqkvT = (u16*)(ws + (8u  << 20));          // 3072x1024  (6 MB)
    u16* WoT   = (u16*)(ws + (14u << 20));          // 1024x1024  (2 MB)
    u16* Qb    = (u16*)(ws + (16u << 20));          // (B,H,T,64) (8 MB)
    u16* Kb    = (u16*)(ws + (24u << 20));          // (B,H,T,64) (8 MB)
    u16* Vt    = (u16*)(ws + (32u << 20));          // (B,H,64,T) (8 MB)
    u16* attn  = (u16*)(ws + (40u << 20));          // (B,T,C)    (8 MB)

    prep_kernel<<<6144, 256, 0, stream>>>(x, xb, Wqkv, WqkvT, Wo, WoT);

    // qkv = x @ W_qkv: 256^2/8-phase GEMM, scattered to Q (pre-scaled) /
    // K (B,H,T,64) / V^T (B,H,64,T).  Grid 192 = 12x16 tiles, 1 block/CU.
    gemm_qkv<<<192, 512, 0, stream>>>(xb, WqkvT, Qb, Kb, Vt);

    attn_kernel<<<dim3(16, BB * HH), 256, 0, stream>>>(Qb, Kb, Vt, attn);

    // out = attn @ W_o  (fp32 store to d_out); BN=64 -> 512 blocks = 2/CU
    gemm_bt<0, 64><<<dim3(CD / 64, BT / 128), 256, 0, stream>>>(
        attn, WoT, nullptr, nullptr, nullptr, out, BT, CD, CD);
}

// Round 2
// 185.917 us; speedup vs baseline: 1.1112x; 1.1112x over previous
//
#include <hip/hip_runtime.h>

typedef unsigned short u16;
typedef unsigned int u32;
typedef __bf16 bf16x8 __attribute__((ext_vector_type(8)));
typedef float f32x4 __attribute__((ext_vector_type(4)));

#define DEV __device__ __forceinline__

// Problem constants (B,T,D_MODEL,H) = (2,2048,1024,16)
constexpr int BB = 2;
constexpr int TT = 2048;
constexpr int CD = 1024;
constexpr int HH = 16;
constexpr int DH = 64;
constexpr int BT = BB * TT;   // 4096

// softmax scale 1/8 folded with log2(e): S' = S/8*log2e, exp(x)=exp2(x')
#define QSCALE 0.18033688011112042f

DEV u16 f2bf(float f) {
    u32 u = __builtin_bit_cast(u32, f);
    u32 r = u + 0x7FFFu + ((u >> 16) & 1u);
    return (u16)(r >> 16);
}

DEV f32x4 mfma16(bf16x8 a, bf16x8 b, f32x4 c) {
    return __builtin_amdgcn_mfma_f32_16x16x32_bf16(a, b, c, 0, 0, 0);
}

// Async global->LDS, 16B per lane: LDS dest = wave-uniform base + lane*16.
DEV void gld_lds16(u16* lds, const u16* g) {
    __builtin_amdgcn_global_load_lds(
        (const __attribute__((address_space(1))) unsigned int*)g,
        (__attribute__((address_space(3))) unsigned int*)lds, 16, 0, 0);
}

// ---------------------------------------------------------------------------
// Fused preprocessing (single launch):
//   blocks [0,2048):      x fp32 -> bf16           (4096x1024)
//   blocks [2048,5120):   W_qkv (1024x3072) -> transposed bf16 (3072x1024)
//   blocks [5120,6144):   W_o   (1024x1024) -> transposed bf16 (1024x1024)
// ---------------------------------------------------------------------------
__global__ __launch_bounds__(256)
void prep_kernel(const float* __restrict__ x, u16* __restrict__ xb,
                 const float* __restrict__ Wqkv, u16* __restrict__ WqkvT,
                 const float* __restrict__ Wo, u16* __restrict__ WoT) {
    const int tid = threadIdx.x;
    int blk = blockIdx.x;
    if (blk < 2048) {                       // convert job
        const int i = (blk * 256 + tid) * 8;
        float4 a = *(const float4*)&x[i];
        float4 b = *(const float4*)&x[i + 4];
        u16 t[8];
        t[0] = f2bf(a.x); t[1] = f2bf(a.y); t[2] = f2bf(a.z); t[3] = f2bf(a.w);
        t[4] = f2bf(b.x); t[5] = f2bf(b.y); t[6] = f2bf(b.z); t[7] = f2bf(b.w);
        *(uint4*)&xb[i] = *(const uint4*)t;
        return;                             // whole block exits (no barrier)
    }
    __shared__ u16 tile[32][33];
    const float* in; u16* out; int rows, cols, bx, by;
    if (blk < 5120) { blk -= 2048; in = Wqkv; out = WqkvT; rows = 1024; cols = 3072; bx = blk % 96; by = blk / 96; }
    else            { blk -= 5120; in = Wo;   out = WoT;   rows = 1024; cols = 1024; bx = blk % 32; by = blk / 32; }
    const int c0 = bx * 32, r0 = by * 32;
    const int tx = tid & 31, ty = tid >> 5;
    #pragma unroll
    for (int i = ty; i < 32; i += 8)
        tile[i][tx] = f2bf(in[(r0 + i) * cols + (c0 + tx)]);
    __syncthreads();
    #pragma unroll
    for (int i = ty; i < 32; i += 8)
        out[(c0 + i) * rows + (r0 + tx)] = tile[tx][i];
}

// ---------------------------------------------------------------------------
// GEMM (2-phase double-buffered): C[M][N] = A[M][K] * Bt[N][K]^T, bf16->fp32.
// BM=128, BN template (128 or 64), BK=32.  T3-minimum recipe (guide §5.5):
//   prologue: STAGE(buf0, t0); __syncthreads();
//   loop t:   STAGE(buf^1, t+1); ds_read buf; MFMA; __syncthreads();
// __syncthreads() = vmcnt(0)+lgkmcnt(0)+s_barrier -- exactly the RAW/WAR
// waits needed, and next-tile loads get the whole compute phase as cover
// (vs the m97 structure where loads were consumed right after the barrier).
// LDS: 2 x (BM+BN)*32*2B = 32 KiB (BN=128) -> 3 blocks/CU at grid 768
// (exactly co-resident, zero quantization).  T1 XCD-chunked block swizzle
// (grid % 8 == 0, bijective).  T2/T5 skipped: measured null in 2-phase
// regime (guide regime-gate table).
// EPI==0: fp32 store to outf.  EPI==1: QKV scatter (bf16 Q,K,V^T); Q is
// pre-scaled by QSCALE (softmax scale + log2e folded in).
// GX = N/BN (grid decoded from 1D blockIdx.x, NBLK = GX*32).
// ---------------------------------------------------------------------------
template <int EPI, int BN, int GX>
__global__ __launch_bounds__(256)
void gemm_db(const u16* __restrict__ A, const u16* __restrict__ Bt,
             u16* __restrict__ out0, u16* __restrict__ out1,
             u16* __restrict__ out2, float* __restrict__ outf,
             int M, int N, int K) {
    constexpr int BM = 128, BK = 32, AST = 32;
    constexpr int NT = BN / 32;             // n-tiles per wave
    constexpr int NBLK = GX * 32;           // M/BM = 32 always here
    constexpr int CPX = NBLK / 8;           // blocks per XCD chunk
    __shared__ alignas(16) u16 As[2][BM * AST];
    __shared__ alignas(16) u16 Bs[2][BN * AST];

    const int tid  = threadIdx.x;
    const int wave = tid >> 6, lane = tid & 63;
    const int quad = lane >> 4, l16 = lane & 15;
    const int wm = (wave & 1) * 64, wn = (wave >> 1) * (BN / 2);

    // T1: XCD-aware chunked swizzle (bijective since NBLK % 8 == 0)
    int bid = (int)blockIdx.x;
    bid = (bid & 7) * CPX + (bid >> 3);
    const int bx = bid % GX, by = bid / GX;
    const int m0 = by * BM, n0 = bx * BN;

    // DMA staging: one instr = 64 lanes x 16B = 16 rows x 64B.
    const int srowA = wave * 32 + (lane >> 2);
    const int srowB = wave * (BN / 4) + (lane >> 2);
    const int scol  = (lane & 3) * 8;
    const u16* ga0 = A  + (size_t)(m0 + srowA) * K + scol;
    const u16* ga1 = ga0 + (size_t)16 * K;
    const u16* gb0 = Bt + (size_t)(n0 + srowB) * K + scol;
    const u16* gb1 = gb0 + (size_t)16 * K;

    auto stage = [&](int buf, int k0) {
        gld_lds16(&As[buf][wave * 1024],           ga0 + k0);
        gld_lds16(&As[buf][wave * 1024 + 512],     ga1 + k0);
        gld_lds16(&Bs[buf][wave * (BN * 8)],       gb0 + k0);
        if constexpr (BN == 128)
            gld_lds16(&Bs[buf][wave * (BN * 8) + 512], gb1 + k0);
    };

    f32x4 acc[4][NT] = {};

    stage(0, 0);
    __syncthreads();

    int cur = 0;
    for (int k0 = 0; k0 < K; k0 += BK, cur ^= 1) {
        if (k0 + BK < K) stage(cur ^ 1, k0 + BK);   // issue-early: full cover

        bf16x8 fa[4], fb[NT];
        #pragma unroll
        for (int mt = 0; mt < 4; ++mt)
            fa[mt] = *(const bf16x8*)&As[cur][(wm + mt * 16 + l16) * AST + quad * 8];
        #pragma unroll
        for (int nt = 0; nt < NT; ++nt)
            fb[nt] = *(const bf16x8*)&Bs[cur][(wn + nt * 16 + l16) * AST + quad * 8];
        #pragma unroll
        for (int mt = 0; mt < 4; ++mt)
            #pragma unroll
            for (int nt = 0; nt < NT; ++nt)
                acc[mt][nt] = mfma16(fa[mt], fb[nt], acc[mt][nt]);
        __syncthreads();            // vmcnt(0)+lgkmcnt(0)+barrier: buf^1 ready
    }

    // Epilogue. C/D layout: row = quad*4+reg, col = l16.
    #pragma unroll
    for (int mt = 0; mt < 4; ++mt) {
        #pragma unroll
        for (int nt = 0; nt < NT; ++nt) {
            #pragma unroll
            for (int reg = 0; reg < 4; ++reg) {
                const int r = m0 + wm + mt * 16 + quad * 4 + reg;
                const int c = n0 + wn + nt * 16 + l16;
                if (EPI == 0) {
                    outf[(size_t)r * N + c] = acc[mt][nt][reg];
                } else {
                    const int which = c >> 10;       // 0=q 1=k 2=v
                    const int cc = c & 1023;
                    const int h = cc >> 6, d = cc & 63;
                    const int b = r >> 11, t = r & 2047;
                    const int bh = b * HH + h;
                    if (which == 0) {
                        out0[((size_t)bh * TT + t) * DH + d] =
                            f2bf(acc[mt][nt][reg] * QSCALE);
                    } else if (which == 1) {
                        out1[((size_t)bh * TT + t) * DH + d] = f2bf(acc[mt][nt][reg]);
                    } else {
                        out2[((size_t)bh * DH + d) * TT + t] = f2bf(acc[mt][nt][reg]);
                    }
                }
            }
        }
    }
}

// ---------------------------------------------------------------------------
// Flash attention v4 (causal): S^T formulation + paired-key full-K=32 PV.
//   S^T = K·Q^T  ->  C[key = quad*4+reg (tile nt)][q = l16]; per-lane scalar
//   softmax state in exp2 domain (scale+log2e pre-folded into Q).
//   PV uses the MFMA k-permutation freedom: logical k=quad*8+j maps to
//   physical key pair*32 + (j<4 ? quad*4+j : 16+quad*4+(j-4)) on BOTH
//   operands (cancels). P^T comes directly from the two C-layout S-tiles;
//   V^T LDS columns are stored pair-permuted so fragments are one b128.
// Grid (16, B*H); block p handles q-tiles 31-p and p (33 steps, balanced).
// K/V double-buffered in LDS; next chunk prefetched to registers; K/V
// fragments hoisted once per chunk and shared by both q-tiles.
// ---------------------------------------------------------------------------
constexpr int KST = 72;  // K/V LDS row stride (144 B, rows 16B-aligned)

DEV void attn_step(const bf16x8 fk[4][2], const bf16x8 fv[2][4],
                   const bf16x8* fq, f32x4* Oacc,
                   float& m_i, float& l_i, bool diag,
                   int wave, int quad, int l16) {
    // S^T: 4 key-tiles x 2 k-steps over d
    f32x4 st[4];
    #pragma unroll
    for (int nt = 0; nt < 4; ++nt) {
        f32x4 t = {};
        t = mfma16(fk[nt][0], fq[0], t);   // A=K (m=key), B=Q (n=q)
        t = mfma16(fk[nt][1], fq[1], t);
        st[nt] = t;
    }

    // causal mask on diagonal tile: key_loc <= q_loc
    if (diag) {
        const int qg = wave * 16 + l16;
        #pragma unroll
        for (int nt = 0; nt < 4; ++nt)
            #pragma unroll
            for (int reg = 0; reg < 4; ++reg) {
                const int kg = nt * 16 + quad * 4 + reg;
                st[nt][reg] = (kg <= qg) ? st[nt][reg] : -INFINITY;
            }
    }

    // row max: 15 in-register + 2 cross-quad shuffles (lane = quad*16+l16)
    float vmax = st[0][0];
    #pragma unroll
    for (int nt = 0; nt < 4; ++nt)
        #pragma unroll
        for (int reg = 0; reg < 4; ++reg)
            vmax = fmaxf(vmax, st[nt][reg]);
    vmax = fmaxf(vmax, __shfl_xor(vmax, 16, 64));
    vmax = fmaxf(vmax, __shfl_xor(vmax, 32, 64));

    const float mnew = fmaxf(m_i, vmax);
    const float alpha = __builtin_amdgcn_exp2f(m_i - mnew);
    m_i = mnew;

    float vsum = 0.f;
    #pragma unroll
    for (int nt = 0; nt < 4; ++nt)
        #pragma unroll
        for (int reg = 0; reg < 4; ++reg) {
            const float p = __builtin_amdgcn_exp2f(st[nt][reg] - mnew);
            st[nt][reg] = p;
            vsum += p;
        }
    vsum += __shfl_xor(vsum, 16, 64);
    vsum += __shfl_xor(vsum, 32, 64);
    l_i = l_i * alpha + vsum;

    #pragma unroll
    for (int dt = 0; dt < 4; ++dt)
        #pragma unroll
        for (int reg = 0; reg < 4; ++reg)
            Oacc[dt][reg] *= alpha;

    // P^T B-operand: reg j<4 = st[2p][j] (key p*32+quad*4+j),
    //                reg j>=4 = st[2p+1][j-4] (key p*32+16+quad*4+j-4)
    #pragma unroll
    for (int pair = 0; pair < 2; ++pair) {
        u16 pa[8];
        #pragma unroll
        for (int j = 0; j < 4; ++j) {
            pa[j]     = f2bf(st[2 * pair][j]);
            pa[4 + j] = f2bf(st[2 * pair + 1][j]);
        }
        const bf16x8 pb = *(const bf16x8*)pa;
        #pragma unroll
        for (int dt = 0; dt < 4; ++dt)
            Oacc[dt] = mfma16(fv[pair][dt], pb, Oacc[dt]);
    }
}

__global__ __launch_bounds__(256, 2)
void attn_kernel(const u16* __restrict__ Q, const u16* __restrict__ Kb,
                 const u16* __restrict__ Vt, u16* __restrict__ O) {
    __shared__ alignas(16) u16 Ks[2][64 * KST];
    __shared__ alignas(16) u16 Vs[2][64 * KST];

    const int p = blockIdx.x;         // 0..15
    const int bh = blockIdx.y;
    const int qtA = 31 - p;           // big tile; also jmax
    const int qtB = p;                // small tile
    const int jmax = qtA;

    const int tid = threadIdx.x;
    const int wave = tid >> 6, lane = tid & 63;
    const int quad = lane >> 4, l16 = lane & 15;

    const u16* Qh = Q  + (size_t)bh * TT * DH;
    const u16* Kh = Kb + (size_t)bh * TT * DH;
    const u16* Vh = Vt + (size_t)bh * DH * TT;

    const int rowA = qtA * 64 + wave * 16;
    const int rowB = qtB * 64 + wave * 16;

    // Q fragments (B-operand: n = l16 = q, k = quad*8+j over d)
    bf16x8 fqA[2], fqB[2];
    fqA[0] = *(const bf16x8*)&Qh[(rowA + l16) * DH + quad * 8];
    fqA[1] = *(const bf16x8*)&Qh[(rowA + l16) * DH + 32 + quad * 8];
    fqB[0] = *(const bf16x8*)&Qh[(rowB + l16) * DH + quad * 8];
    fqB[1] = *(const bf16x8*)&Qh[(rowB + l16) * DH + 32 + quad * 8];

    f32x4 OA[4] = {}, OB[4] = {};
    float mA = -INFINITY, lA = 0.f, mB = -INFINITY, lB = 0.f;

    // Chunk staging: thread i covers 16B at row (i>>3), col (i&7)*8, +row32.
    const int trow = tid >> 3;
    const int ic   = tid & 7;            // 8-key group index
    const int tcol = ic * 8;
    // V pair-permuted destination column for this thread's 8 keys:
    //   keys 8*ic..8*ic+7 -> cols c1..c1+3 and c1+8..c1+11
    const int vc1 = 32 * (ic >> 2) + 16 * (ic & 1) + 4 * ((ic & 3) >> 1);
    uint4 kr0, kr1, vr0, vr1;

    auto load_chunk = [&](int j) {
        const u16* ks = Kh + (size_t)j * 64 * DH;
        kr0 = *(const uint4*)&ks[trow * DH + tcol];
        kr1 = *(const uint4*)&ks[(trow + 32) * DH + tcol];
        const u16* vs = Vh + (size_t)j * 64;
        vr0 = *(const uint4*)&vs[(size_t)trow * TT + tcol];
        vr1 = *(const uint4*)&vs[(size_t)(trow + 32) * TT + tcol];
    };
    auto write_chunk = [&](int buf) {
        *(uint4*)&Ks[buf][trow * KST + tcol]        = kr0;
        *(uint4*)&Ks[buf][(trow + 32) * KST + tcol] = kr1;
        // V: split each 16B into two 8B halves at permuted columns
        *(uint2*)&Vs[buf][trow * KST + vc1]            = *(const uint2*)&vr0;
        *(uint2*)&Vs[buf][trow * KST + vc1 + 8]        = *((const uint2*)&vr0 + 1);
        *(uint2*)&Vs[buf][(trow + 32) * KST + vc1]     = *(const uint2*)&vr1;
        *(uint2*)&Vs[buf][(trow + 32) * KST + vc1 + 8] = *((const uint2*)&vr1 + 1);
    };

    load_chunk(0);
    write_chunk(0);

    for (int j = 0; j <= jmax; ++j) {
        const int cur = j & 1;
        __syncthreads();                    // buf[cur] staged & visible
        if (j < jmax) load_chunk(j + 1);    // loads fly during compute

        // Hoist K/V fragments once per chunk (shared by both q-tiles)
        bf16x8 fk[4][2], fv[2][4];
        #pragma unroll
        for (int nt = 0; nt < 4; ++nt) {
            fk[nt][0] = *(const bf16x8*)&Ks[cur][(nt * 16 + l16) * KST + quad * 8];
            fk[nt][1] = *(const bf16x8*)&Ks[cur][(nt * 16 + l16) * KST + 32 + quad * 8];
        }
        #pragma unroll
        for (int pair = 0; pair < 2; ++pair)
            #pragma unroll
            for (int dt = 0; dt < 4; ++dt)
                fv[pair][dt] = *(const bf16x8*)
                    &Vs[cur][(dt * 16 + l16) * KST + pair * 32 + quad * 8];

        attn_step(fk, fv, fqA, OA, mA, lA, (j == qtA), wave, quad, l16);
        if (j <= qtB)
            attn_step(fk, fv, fqB, OB, mB, lB, (j == qtB), wave, quad, l16);
        if (j < jmax) write_chunk(cur ^ 1); // after all buf[cur^1] readers done
    }

    // Epilogue: O^T rows d = dt*16+quad*4+reg, col q = l16; write (B,T,C).
    const int b = bh >> 4, h = bh & 15;
    const float rA = 1.f / lA, rB = 1.f / lB;
    #pragma unroll
    for (int dt = 0; dt < 4; ++dt) {
        u16 oa[4], ob[4];
        #pragma unroll
        for (int reg = 0; reg < 4; ++reg) {
            oa[reg] = f2bf(OA[dt][reg] * rA);
            ob[reg] = f2bf(OB[dt][reg] * rB);
        }
        *(uint2*)&O[((size_t)(b * TT + rowA + l16)) * CD + h * DH + dt * 16 + quad * 4] =
            *(const uint2*)oa;
        *(uint2*)&O[((size_t)(b * TT + rowB + l16)) * CD + h * DH + dt * 16 + quad * 4] =
            *(const uint2*)ob;
    }
}

// ---------------------------------------------------------------------------
extern "C" void kernel_launch(void* const* d_in, const int* in_sizes, int n_in,
                              void* d_out, int out_size, void* d_ws, size_t ws_size,
                              hipStream_t stream) {
    (void)in_sizes; (void)n_in; (void)out_size; (void)ws_size;
    const float* x    = (const float*)d_in[0];   // (4096, 1024) fp32
    const float* Wqkv = (const float*)d_in[1];   // (1024, 3072) fp32
    const float* Wo   = (const float*)d_in[2];   // (1024, 1024) fp32
    float* out = (float*)d_out;                  // (4096, 1024) fp32

    char* ws = (char*)d_ws;
    u16* xb    = (u16*)(ws + 0);                    // 4096x1024  (8 MB)
    u16* WqkvT = (u16*)(ws + (8u  << 20));          // 3072x1024  (6 MB)
    u16* WoT   = (u16*)(ws + (14u << 20));          // 1024x1024  (2 MB)
    u16* Qb    = (u16*)(ws + (16u << 20));          // (B,H,T,64) (8 MB)
    u16* Kb    = (u16*)(ws + (24u << 20));          // (B,H,T,64) (8 MB)
    u16* Vt    = (u16*)(ws + (32u << 20));          // (B,H,64,T) (8 MB)
    u16* attn  = (u16*)(ws + (40u << 20));          // (B,T,C)    (8 MB)

    prep_kernel<<<6144, 256, 0, stream>>>(x, xb, Wqkv, WqkvT, Wo, WoT);

    // qkv = x @ W_qkv (2-phase dbuf, 128x128): grid 768 = 3 blocks/CU exact.
    gemm_db<1, 128, 24><<<768, 256, 0, stream>>>(
        xb, WqkvT, Qb, Kb, Vt, nullptr, BT, 3072, CD);

    attn_kernel<<<dim3(16, BB * HH), 256, 0, stream>>>(Qb, Kb, Vt, attn);

    // out = attn @ W_o (2-phase dbuf, 128x64): grid 512 = 2 blocks/CU exact.
    gemm_db<0, 64, 16><<<512, 256, 0, stream>>>(
        attn, WoT, nullptr, nullptr, nullptr, out, BT, CD, CD);
}

// Round 3
// 177.577 us; speedup vs baseline: 1.1634x; 1.0470x over previous
//
#include <hip/hip_runtime.h>

typedef unsigned short u16;
typedef unsigned int u32;
typedef __bf16 bf16x8 __attribute__((ext_vector_type(8)));
typedef float f32x4 __attribute__((ext_vector_type(4)));

#define DEV __device__ __forceinline__

// Problem constants (B,T,D_MODEL,H) = (2,2048,1024,16)
constexpr int BB = 2;
constexpr int TT = 2048;
constexpr int CD = 1024;
constexpr int HH = 16;
constexpr int DH = 64;
constexpr int BT = BB * TT;   // 4096

// softmax scale 1/8 folded with log2(e): S' = S/8*log2e, exp(x)=exp2(x')
#define QSCALE 0.18033688011112042f

// Native bf16 convert (RTNE): lets the compiler pack pairs into
// v_cvt_pk_bf16_f32 (guide m240: scalar casts vectorize; manual bit-twiddle
// blocks it and costs ~5 VALU ops/value).
DEV u16 f2bf(float f) {
    return __builtin_bit_cast(u16, (__bf16)f);
}

DEV f32x4 mfma16(bf16x8 a, bf16x8 b, f32x4 c) {
    return __builtin_amdgcn_mfma_f32_16x16x32_bf16(a, b, c, 0, 0, 0);
}

// Async global->LDS, 16B per lane: LDS dest = wave-uniform base + lane*16.
DEV void gld_lds16(u16* lds, const u16* g) {
    __builtin_amdgcn_global_load_lds(
        (const __attribute__((address_space(1))) unsigned int*)g,
        (__attribute__((address_space(3))) unsigned int*)lds, 16, 0, 0);
}

// ---------------------------------------------------------------------------
// Fused preprocessing (single launch):
//   blocks [0,2048):      x fp32 -> bf16           (4096x1024)
//   blocks [2048,5120):   W_qkv (1024x3072) -> transposed bf16 (3072x1024)
//   blocks [5120,6144):   W_o   (1024x1024) -> transposed bf16 (1024x1024)
// ---------------------------------------------------------------------------
__global__ __launch_bounds__(256)
void prep_kernel(const float* __restrict__ x, u16* __restrict__ xb,
                 const float* __restrict__ Wqkv, u16* __restrict__ WqkvT,
                 const float* __restrict__ Wo, u16* __restrict__ WoT) {
    const int tid = threadIdx.x;
    int blk = blockIdx.x;
    if (blk < 2048) {                       // convert job
        const int i = (blk * 256 + tid) * 8;
        float4 a = *(const float4*)&x[i];
        float4 b = *(const float4*)&x[i + 4];
        u16 t[8];
        t[0] = f2bf(a.x); t[1] = f2bf(a.y); t[2] = f2bf(a.z); t[3] = f2bf(a.w);
        t[4] = f2bf(b.x); t[5] = f2bf(b.y); t[6] = f2bf(b.z); t[7] = f2bf(b.w);
        *(uint4*)&xb[i] = *(const uint4*)t;
        return;                             // whole block exits (no barrier)
    }
    __shared__ u16 tile[32][33];
    const float* in; u16* out; int rows, cols, bx, by;
    if (blk < 5120) { blk -= 2048; in = Wqkv; out = WqkvT; rows = 1024; cols = 3072; bx = blk % 96; by = blk / 96; }
    else            { blk -= 5120; in = Wo;   out = WoT;   rows = 1024; cols = 1024; bx = blk % 32; by = blk / 32; }
    const int c0 = bx * 32, r0 = by * 32;
    const int tx = tid & 31, ty = tid >> 5;
    #pragma unroll
    for (int i = ty; i < 32; i += 8)
        tile[i][tx] = f2bf(in[(r0 + i) * cols + (c0 + tx)]);
    __syncthreads();
    #pragma unroll
    for (int i = ty; i < 32; i += 8)
        out[(c0 + i) * rows + (r0 + tx)] = tile[tx][i];
}

// ---------------------------------------------------------------------------
// GEMM (2-phase double-buffered): C[M][N] = A[M][K] * Bt[N][K]^T, bf16->fp32.
// BM=128, BN template (128 or 64), BK=32.  T3-minimum recipe (guide §5.5).
// T1 XCD-chunked block swizzle (grid % 8 == 0, bijective).
// EPI==0: fp32 store to outf.  EPI==1: QKV scatter (bf16 Q,K,V^T); Q is
// pre-scaled by QSCALE (softmax scale + log2e folded in).
// ---------------------------------------------------------------------------
template <int EPI, int BN, int GX>
__global__ __launch_bounds__(256)
void gemm_db(const u16* __restrict__ A, const u16* __restrict__ Bt,
             u16* __restrict__ out0, u16* __restrict__ out1,
             u16* __restrict__ out2, float* __restrict__ outf,
             int M, int N, int K) {
    constexpr int BM = 128, BK = 32, AST = 32;
    constexpr int NT = BN / 32;             // n-tiles per wave
    constexpr int NBLK = GX * 32;           // M/BM = 32 always here
    constexpr int CPX = NBLK / 8;           // blocks per XCD chunk
    __shared__ alignas(16) u16 As[2][BM * AST];
    __shared__ alignas(16) u16 Bs[2][BN * AST];

    const int tid  = threadIdx.x;
    const int wave = tid >> 6, lane = tid & 63;
    const int quad = lane >> 4, l16 = lane & 15;
    const int wm = (wave & 1) * 64, wn = (wave >> 1) * (BN / 2);

    // T1: XCD-aware chunked swizzle (bijective since NBLK % 8 == 0)
    int bid = (int)blockIdx.x;
    bid = (bid & 7) * CPX + (bid >> 3);
    const int bx = bid % GX, by = bid / GX;
    const int m0 = by * BM, n0 = bx * BN;

    // DMA staging: one instr = 64 lanes x 16B = 16 rows x 64B.
    const int srowA = wave * 32 + (lane >> 2);
    const int srowB = wave * (BN / 4) + (lane >> 2);
    const int scol  = (lane & 3) * 8;
    const u16* ga0 = A  + (size_t)(m0 + srowA) * K + scol;
    const u16* ga1 = ga0 + (size_t)16 * K;
    const u16* gb0 = Bt + (size_t)(n0 + srowB) * K + scol;
    const u16* gb1 = gb0 + (size_t)16 * K;

    auto stage = [&](int buf, int k0) {
        gld_lds16(&As[buf][wave * 1024],           ga0 + k0);
        gld_lds16(&As[buf][wave * 1024 + 512],     ga1 + k0);
        gld_lds16(&Bs[buf][wave * (BN * 8)],       gb0 + k0);
        if constexpr (BN == 128)
            gld_lds16(&Bs[buf][wave * (BN * 8) + 512], gb1 + k0);
    };

    f32x4 acc[4][NT] = {};

    stage(0, 0);
    __syncthreads();

    int cur = 0;
    for (int k0 = 0; k0 < K; k0 += BK, cur ^= 1) {
        if (k0 + BK < K) stage(cur ^ 1, k0 + BK);   // issue-early: full cover

        bf16x8 fa[4], fb[NT];
        #pragma unroll
        for (int mt = 0; mt < 4; ++mt)
            fa[mt] = *(const bf16x8*)&As[cur][(wm + mt * 16 + l16) * AST + quad * 8];
        #pragma unroll
        for (int nt = 0; nt < NT; ++nt)
            fb[nt] = *(const bf16x8*)&Bs[cur][(wn + nt * 16 + l16) * AST + quad * 8];
        #pragma unroll
        for (int mt = 0; mt < 4; ++mt)
            #pragma unroll
            for (int nt = 0; nt < NT; ++nt)
                acc[mt][nt] = mfma16(fa[mt], fb[nt], acc[mt][nt]);
        __syncthreads();            // vmcnt(0)+lgkmcnt(0)+barrier: buf^1 ready
    }

    // Epilogue. C/D layout: row = quad*4+reg, col = l16.
    #pragma unroll
    for (int mt = 0; mt < 4; ++mt) {
        #pragma unroll
        for (int nt = 0; nt < NT; ++nt) {
            #pragma unroll
            for (int reg = 0; reg < 4; ++reg) {
                const int r = m0 + wm + mt * 16 + quad * 4 + reg;
                const int c = n0 + wn + nt * 16 + l16;
                if (EPI == 0) {
                    outf[(size_t)r * N + c] = acc[mt][nt][reg];
                } else {
                    const int which = c >> 10;       // 0=q 1=k 2=v
                    const int cc = c & 1023;
                    const int h = cc >> 6, d = cc & 63;
                    const int b = r >> 11, t = r & 2047;
                    const int bh = b * HH + h;
                    if (which == 0) {
                        out0[((size_t)bh * TT + t) * DH + d] =
                            f2bf(acc[mt][nt][reg] * QSCALE);
                    } else if (which == 1) {
                        out1[((size_t)bh * TT + t) * DH + d] = f2bf(acc[mt][nt][reg]);
                    } else {
                        out2[((size_t)bh * DH + d) * TT + t] = f2bf(acc[mt][nt][reg]);
                    }
                }
            }
        }
    }
}

// ---------------------------------------------------------------------------
// Flash attention v5 (causal): S^T formulation + paired-key full-K=32 PV.
// One q-tile (64 rows, 4 waves x 16 rows) per block; grid 1024 blocks
// (32 q-tiles x 32 bh) -> 4 blocks/CU, 16 waves/CU (vs 8 before: the serial
// softmax chain is now hidden by TLP).  Dispatch longest-qt-first; bh->XCD
// swizzle (bid&7 = XCD hosts bh%8 == that value: 4 heads' K+V = 2 MB per
// 4 MB XCD L2).  Softmax: tree max/sum (depth 4), native bf16 converts.
// K/V double-buffered in LDS; next chunk prefetched to registers.
// ---------------------------------------------------------------------------
constexpr int KST = 72;  // K/V LDS row stride (144 B, rows 16B-aligned)

DEV void attn_step(const bf16x8 fk[4][2], const bf16x8 fv[2][4],
                   const bf16x8* fq, f32x4* Oacc,
                   float& m_i, float& l_i, bool diag,
                   int wave, int quad, int l16) {
    // S^T: 4 key-tiles x 2 k-steps over d
    f32x4 st[4];
    #pragma unroll
    for (int nt = 0; nt < 4; ++nt) {
        f32x4 t = {};
        t = mfma16(fk[nt][0], fq[0], t);   // A=K (m=key), B=Q (n=q)
        t = mfma16(fk[nt][1], fq[1], t);
        st[nt] = t;
    }

    // causal mask on diagonal tile: key_loc <= q_loc
    if (diag) {
        const int qg = wave * 16 + l16;
        #pragma unroll
        for (int nt = 0; nt < 4; ++nt)
            #pragma unroll
            for (int reg = 0; reg < 4; ++reg) {
                const int kg = nt * 16 + quad * 4 + reg;
                st[nt][reg] = (kg <= qg) ? st[nt][reg] : -INFINITY;
            }
    }

    // row max: depth-4 tree + 2 cross-quad shuffles (lane = quad*16+l16)
    float v[16];
    #pragma unroll
    for (int nt = 0; nt < 4; ++nt)
        #pragma unroll
        for (int reg = 0; reg < 4; ++reg)
            v[nt * 4 + reg] = st[nt][reg];
    #pragma unroll
    for (int s = 8; s > 0; s >>= 1)
        #pragma unroll
        for (int i = 0; i < s; ++i)
            v[i] = fmaxf(v[i], v[i + s]);
    float vmax = v[0];
    vmax = fmaxf(vmax, __shfl_xor(vmax, 16, 64));
    vmax = fmaxf(vmax, __shfl_xor(vmax, 32, 64));

    const float mnew = fmaxf(m_i, vmax);
    const float alpha = __builtin_amdgcn_exp2f(m_i - mnew);
    m_i = mnew;

    #pragma unroll
    for (int nt = 0; nt < 4; ++nt)
        #pragma unroll
        for (int reg = 0; reg < 4; ++reg) {
            const float p = __builtin_amdgcn_exp2f(st[nt][reg] - mnew);
            st[nt][reg] = p;
            v[nt * 4 + reg] = p;
        }
    #pragma unroll
    for (int s = 8; s > 0; s >>= 1)
        #pragma unroll
        for (int i = 0; i < s; ++i)
            v[i] += v[i + s];
    float vsum = v[0];
    vsum += __shfl_xor(vsum, 16, 64);
    vsum += __shfl_xor(vsum, 32, 64);
    l_i = l_i * alpha + vsum;

    #pragma unroll
    for (int dt = 0; dt < 4; ++dt)
        #pragma unroll
        for (int reg = 0; reg < 4; ++reg)
            Oacc[dt][reg] *= alpha;

    // P^T B-operand: reg j<4 = st[2p][j] (key p*32+quad*4+j),
    //                reg j>=4 = st[2p+1][j-4] (key p*32+16+quad*4+j-4)
    #pragma unroll
    for (int pair = 0; pair < 2; ++pair) {
        bf16x8 pb;
        #pragma unroll
        for (int j = 0; j < 4; ++j) {
            pb[j]     = (__bf16)st[2 * pair][j];
            pb[4 + j] = (__bf16)st[2 * pair + 1][j];
        }
        #pragma unroll
        for (int dt = 0; dt < 4; ++dt)
            Oacc[dt] = mfma16(fv[pair][dt], pb, Oacc[dt]);
    }
}

__global__ __launch_bounds__(256, 4)
void attn_kernel(const u16* __restrict__ Q, const u16* __restrict__ Kb,
                 const u16* __restrict__ Vt, u16* __restrict__ O) {
    __shared__ alignas(16) u16 Ks[2][64 * KST];
    __shared__ alignas(16) u16 Vs[2][64 * KST];

    // Decode: bid[2:0]=xcd (hosts bh with bh&7==xcd), bid[4:3]=bh>>3,
    // bid[9:5]=31-qt (longest q-tile dispatched first).
    const int bid = (int)blockIdx.x;
    const int j2 = bid >> 3;
    const int qt = 31 - (j2 >> 2);
    const int bh = (bid & 7) + 8 * (j2 & 3);
    const int jmax = qt;

    const int tid = threadIdx.x;
    const int wave = tid >> 6, lane = tid & 63;
    const int quad = lane >> 4, l16 = lane & 15;

    const u16* Qh = Q  + (size_t)bh * TT * DH;
    const u16* Kh = Kb + (size_t)bh * TT * DH;
    const u16* Vh = Vt + (size_t)bh * DH * TT;

    const int row = qt * 64 + wave * 16;

    // Q fragments (B-operand: n = l16 = q, k = quad*8+j over d)
    bf16x8 fq[2];
    fq[0] = *(const bf16x8*)&Qh[(row + l16) * DH + quad * 8];
    fq[1] = *(const bf16x8*)&Qh[(row + l16) * DH + 32 + quad * 8];

    f32x4 Oa[4] = {};
    float m_i = -INFINITY, l_i = 0.f;

    // Chunk staging: thread i covers 16B at row (i>>3), col (i&7)*8, +row32.
    const int trow = tid >> 3;
    const int ic   = tid & 7;            // 8-key group index
    const int tcol = ic * 8;
    // V pair-permuted destination column for this thread's 8 keys:
    //   keys 8*ic..8*ic+7 -> cols c1..c1+3 and c1+8..c1+11
    const int vc1 = 32 * (ic >> 2) + 16 * (ic & 1) + 4 * ((ic & 3) >> 1);
    uint4 kr0, kr1, vr0, vr1;

    auto load_chunk = [&](int j) {
        const u16* ks = Kh + (size_t)j * 64 * DH;
        kr0 = *(const uint4*)&ks[trow * DH + tcol];
        kr1 = *(const uint4*)&ks[(trow + 32) * DH + tcol];
        const u16* vs = Vh + (size_t)j * 64;
        vr0 = *(const uint4*)&vs[(size_t)trow * TT + tcol];
        vr1 = *(const uint4*)&vs[(size_t)(trow + 32) * TT + tcol];
    };
    auto write_chunk = [&](int buf) {
        *(uint4*)&Ks[buf][trow * KST + tcol]        = kr0;
        *(uint4*)&Ks[buf][(trow + 32) * KST + tcol] = kr1;
        // V: split each 16B into two 8B halves at permuted columns
        *(uint2*)&Vs[buf][trow * KST + vc1]            = *(const uint2*)&vr0;
        *(uint2*)&Vs[buf][trow * KST + vc1 + 8]        = *((const uint2*)&vr0 + 1);
        *(uint2*)&Vs[buf][(trow + 32) * KST + vc1]     = *(const uint2*)&vr1;
        *(uint2*)&Vs[buf][(trow + 32) * KST + vc1 + 8] = *((const uint2*)&vr1 + 1);
    };

    load_chunk(0);
    write_chunk(0);

    for (int j = 0; j <= jmax; ++j) {
        const int cur = j & 1;
        __syncthreads();                    // buf[cur] staged & visible
        if (j < jmax) load_chunk(j + 1);    // loads fly during compute

        // Hoist K/V fragments (issued early; compiler inserts lgkm waits)
        bf16x8 fk[4][2], fv[2][4];
        #pragma unroll
        for (int nt = 0; nt < 4; ++nt) {
            fk[nt][0] = *(const bf16x8*)&Ks[cur][(nt * 16 + l16) * KST + quad * 8];
            fk[nt][1] = *(const bf16x8*)&Ks[cur][(nt * 16 + l16) * KST + 32 + quad * 8];
        }
        #pragma unroll
        for (int pair = 0; pair < 2; ++pair)
            #pragma unroll
            for (int dt = 0; dt < 4; ++dt)
                fv[pair][dt] = *(const bf16x8*)
                    &Vs[cur][(dt * 16 + l16) * KST + pair * 32 + quad * 8];

        attn_step(fk, fv, fq, Oa, m_i, l_i, (j == qt), wave, quad, l16);
        if (j < jmax) write_chunk(cur ^ 1); // after all buf[cur^1] readers done
    }

    // Epilogue: O^T rows d = dt*16+quad*4+reg, col q = l16; write (B,T,C).
    const int b = bh >> 4, h = bh & 15;
    const float r_i = 1.f / l_i;
    #pragma unroll
    for (int dt = 0; dt < 4; ++dt) {
        u16 oa[4];
        #pragma unroll
        for (int reg = 0; reg < 4; ++reg)
            oa[reg] = f2bf(Oa[dt][reg] * r_i);
        *(uint2*)&O[((size_t)(b * TT + row + l16)) * CD + h * DH + dt * 16 + quad * 4] =
            *(const uint2*)oa;
    }
}

// ---------------------------------------------------------------------------
extern "C" void kernel_launch(void* const* d_in, const int* in_sizes, int n_in,
                              void* d_out, int out_size, void* d_ws, size_t ws_size,
                              hipStream_t stream) {
    (void)in_sizes; (void)n_in; (void)out_size; (void)ws_size;
    const float* x    = (const float*)d_in[0];   // (4096, 1024) fp32
    const float* Wqkv = (const float*)d_in[1];   // (1024, 3072) fp32
    const float* Wo   = (const float*)d_in[2];   // (1024, 1024) fp32
    float* out = (float*)d_out;                  // (4096, 1024) fp32

    char* ws = (char*)d_ws;
    u16* xb    = (u16*)(ws + 0);                    // 4096x1024  (8 MB)
    u16* WqkvT = (u16*)(ws + (8u  << 20));          // 3072x1024  (6 MB)
    u16* WoT   = (u16*)(ws + (14u << 20));          // 1024x1024  (2 MB)
    u16* Qb    = (u16*)(ws + (16u << 20));          // (B,H,T,64) (8 MB)
    u16* Kb    = (u16*)(ws + (24u << 20));          // (B,H,T,64) (8 MB)
    u16* Vt    = (u16*)(ws + (32u << 20));          // (B,H,64,T) (8 MB)
    u16* attn  = (u16*)(ws + (40u << 20));          // (B,T,C)    (8 MB)

    prep_kernel<<<6144, 256, 0, stream>>>(x, xb, Wqkv, WqkvT, Wo, WoT);

    // qkv = x @ W_qkv (2-phase dbuf, 128x128): grid 768 = 3 blocks/CU exact.
    gemm_db<1, 128, 24><<<768, 256, 0, stream>>>(
        xb, WqkvT, Qb, Kb, Vt, nullptr, BT, 3072, CD);

    // attn: 1024 single-q-tile blocks, longest-first, bh->XCD locality.
    attn_kernel<<<1024, 256, 0, stream>>>(Qb, Kb, Vt, attn);

    // out = attn @ W_o (2-phase dbuf, 128x64): grid 512 = 2 blocks/CU exact.
    gemm_db<0, 64, 16><<<512, 256, 0, stream>>>(
        attn, WoT, nullptr, nullptr, nullptr, out, BT, CD, CD);
}